// Round 16
// baseline (569.956 us; speedup 1.0000x reference)
//
#include <hip/hip_runtime.h>
#include <hip/hip_bf16.h>
#include <hip/hip_fp8.h>

#define N_ROWS 4096
#define H_DIM  512
#define V_DIM  50257
#define BM 128
#define BN 128
#define BK 64
#define NSTEP (H_DIM / BK)      // 8
#define VT_TOTAL 393            // ceil(V/BN)
#define V_PAD (VT_TOTAL * BN)   // 50304
#define NCHUNK 131              // 393 = 3*131 -> every block exactly 3 tiles
#define LOG2E 1.4426950408889634f
#define WSCALE 32.0f
#define WDESCALE 0.03125f
#define BUF0 0
#define BUF1 16384
#define LBASE 32768             // bf16 L tile, 32 KB (disjoint from staging)

#define VMCNT4() asm volatile("s_waitcnt vmcnt(4)" ::: "memory")
#define VMC0()   asm volatile("s_waitcnt vmcnt(0)" ::: "memory")
#define LGKM0()  asm volatile("s_waitcnt lgkmcnt(0)" ::: "memory")
#define BARRIER() __builtin_amdgcn_s_barrier()

typedef __attribute__((ext_vector_type(8))) short short8;
typedef __attribute__((ext_vector_type(4))) float f32x4;

static __device__ __forceinline__ unsigned short f2bf(float f) {
  unsigned u = __float_as_uint(f);
  u = (u + 0x7fffu + ((u >> 16) & 1u)) >> 16;   // RNE
  return (unsigned short)u;
}

static __device__ __forceinline__ unsigned char f2fp8(float f) {
  __hip_fp8_e4m3 v(f);
  return (unsigned char)v.__x;
}

static __device__ __forceinline__ void gload_lds16(const void* g, void* l) {
  __builtin_amdgcn_global_load_lds(
      (const __attribute__((address_space(1))) void*)g,
      (__attribute__((address_space(3))) void*)l, 16, 0, 0);
}

// ------- kernel A: fp32 -> fp8 e4m3 (W scaled by 32, padded to V_PAD) -----
__global__ void convert_kernel(const float* __restrict__ X,
                               const float* __restrict__ W,
                               unsigned char* __restrict__ Xq,
                               unsigned char* __restrict__ Wq) {
  const long wtot8 = (long)V_PAD * H_DIM / 8;   // 3,219,456
  const long xtot8 = (long)N_ROWS * H_DIM / 8;  //   262,144
  long i = (long)blockIdx.x * blockDim.x + threadIdx.x;
  unsigned char o[8];
  if (i < wtot8) {
    long base = i * 8;
    long row = base >> 9;   // /512
    if (row < V_DIM) {
      const float4* s = (const float4*)(W + base);
      float4 a = s[0], b = s[1];
      o[0]=f2fp8(WSCALE*a.x); o[1]=f2fp8(WSCALE*a.y);
      o[2]=f2fp8(WSCALE*a.z); o[3]=f2fp8(WSCALE*a.w);
      o[4]=f2fp8(WSCALE*b.x); o[5]=f2fp8(WSCALE*b.y);
      o[6]=f2fp8(WSCALE*b.z); o[7]=f2fp8(WSCALE*b.w);
    } else {
      #pragma unroll
      for (int k = 0; k < 8; ++k) o[k] = 0;
    }
    *(uint2*)(Wq + base) = *(const uint2*)o;
  } else if (i < wtot8 + xtot8) {
    long base = (i - wtot8) * 8;
    const float4* s = (const float4*)(X + base);
    float4 a = s[0], b = s[1];
    o[0]=f2fp8(a.x); o[1]=f2fp8(a.y); o[2]=f2fp8(a.z); o[3]=f2fp8(a.w);
    o[4]=f2fp8(b.x); o[5]=f2fp8(b.y); o[6]=f2fp8(b.z); o[7]=f2fp8(b.w);
    *(uint2*)(Xq + base) = *(const uint2*)o;
  }
}

// stats update for one 16-col chunk (Lraw includes bias)
template <bool GUARD>
static __device__ __forceinline__ void stats16(
    const float (&Lraw)[16], const f32x4* T4, int gcol0,
    float& ml, float& sl, float& mt, float& st, float& dd) {
  float Lv[16], Tv[16];
  #pragma unroll
  for (int k = 0; k < 16; ++k) {
    const bool ok = !GUARD || (gcol0 + k < V_DIM);
    Lv[k] = ok ? Lraw[k] : -1e30f;
    Tv[k] = ok ? T4[k >> 2][k & 3] : -1e30f;
  }
  float g = Lv[0];
  #pragma unroll
  for (int k = 1; k < 16; ++k) g = fmaxf(g, Lv[k]);
  if (g > ml + 12.f) { sl *= exp2f((ml - g) * LOG2E); ml = g; }
  float bl = ml * LOG2E;
  float ss = 0.f;
  #pragma unroll
  for (int k = 0; k < 16; ++k) ss += exp2f(__builtin_fmaf(Lv[k], LOG2E, -bl));
  sl += ss;
  float gt = Tv[0];
  #pragma unroll
  for (int k = 1; k < 16; ++k) gt = fmaxf(gt, Tv[k]);
  if (gt > mt + 12.f) {
    float sc = exp2f((mt - gt) * LOG2E);
    st *= sc; dd *= sc; mt = gt;
  }
  float bt = mt * LOG2E;
  float s2 = 0.f, d2 = 0.f;
  #pragma unroll
  for (int k = 0; k < 16; ++k) {
    float e = exp2f(__builtin_fmaf(Tv[k], LOG2E, -bt));
    s2 += e;
    d2 = __builtin_fmaf(e, Lv[k], d2);
  }
  st += s2; dd += d2;
}

// streaming stats for one tile: 64 cols (4 chunks), 2-deep T pipeline.
// L is bf16 in LDS, row stride 256 B, XOR-swizzled by (row&7)<<4.
template <bool GUARD>
static __device__ __forceinline__ void stream_tile(
    const float* __restrict__ targets, const char* __restrict__ Lrow,
    long growVD, int vbase, int cb0, int rsw, long tlim,
    float& mlr, float& slr, float& mtr, float& str, float& ddr) {
  f32x4 T0[4], T1[4];
  auto LOADT = [&](f32x4 (&D)[4], int i) {
    #pragma unroll
    for (int c = 0; c < 4; ++c) {
      long off = growVD + vbase + cb0 + i * 16 + c * 4;
      if (GUARD) off = off > tlim ? tlim : off;
      D[c] = *(const f32x4*)(targets + off);
    }
  };
  auto DOCHUNK = [&](const f32x4 (&T)[4], int i) {
    const int ob = (cb0 << 1) + (i << 5);
    short8 l0 = *(const short8*)(Lrow + ((ob) ^ rsw));
    short8 l1 = *(const short8*)(Lrow + ((ob + 16) ^ rsw));
    float Lraw[16];
    #pragma unroll
    for (int e = 0; e < 8; ++e) {
      Lraw[e]     = __uint_as_float(((unsigned)(unsigned short)l0[e]) << 16);
      Lraw[e + 8] = __uint_as_float(((unsigned)(unsigned short)l1[e]) << 16);
    }
    stats16<GUARD>(Lraw, T, vbase + cb0 + i * 16, mlr, slr, mtr, str, ddr);
  };
  LOADT(T0, 0); LOADT(T1, 1);
  DOCHUNK(T0, 0);
  LOADT(T0, 2);
  DOCHUNK(T1, 1);
  LOADT(T1, 3);
  DOCHUNK(T0, 2);
  DOCHUNK(T1, 3);
}

// ---------------- kernel B: fused fp8 GEMM + online softmax stats ---------
// r8/r15 skeleton with fp8 operands: staging buf 16 KB/step (2x dbuf 32 KB)
// + bf16 L tile 32 KB (disjoint) = 64 KB -> 2 blocks/CU. Frag reads are b64
// (LDS bytes halved). Counted vmcnt(4); ks=7 prefetches next tile's k0.
__global__ __launch_bounds__(256, 2)
void fused_kernel(const unsigned char* __restrict__ Xq,
                  const unsigned char* __restrict__ Wq,
                  const float* __restrict__ bias,
                  const float* __restrict__ targets,
                  float* __restrict__ partials) {
  __shared__ __align__(16) char smem[65536];

  const int tid  = threadIdx.x;
  const int lane = tid & 63;
  const int wid  = tid >> 6;
  const int wm   = wid >> 1;
  const int wn   = wid & 1;
  const int q    = lane >> 4;
  const int c15  = lane & 15;

  // XCD-aware bijective swizzle: nwg = 4192 = 8 * 524
  int f = blockIdx.y * gridDim.x + blockIdx.x;
  f = (f & 7) * 524 + (f >> 3);
  const int brow  = f & 31;
  const int chunk = f >> 5;

  float mlr = -1e30f, slr = 0.f, mtr = -1e30f, str = 0.f, ddr = 0.f;

  // staging: thread t covers row t>>2 (0..63; +64 on 2nd issue), 16B slot
  // t&3. Source slot pre-swizzled (slot16 ^= row&3) so swizzled b64 frag
  // reads are conflict-free while LDS writes stay linear.
  const int srow4 = tid >> 2;                                // 0..63
  const int soff  = (((tid & 3) ^ (srow4 & 3)) * 16);        // bytes in row
  const unsigned char* asrc = Xq + (long)(brow * BM + srow4) * H_DIM + soff;

  // fragment-read precompute: row byte stride 64; in-row offset
  // ((s*2 + (q>>1)) ^ (c15&3))*16 + (q&1)*8
  const int rm3    = c15 & 3;
  const int arow_b = (wm * 64 + c15) * 64;   // + a*1024
  const int brow_b = (wn * 64 + c15) * 64;   // + b*1024 (+8192 B-region)
  const int io[2] = { (((q >> 1)) ^ rm3) * 16 + (q & 1) * 8,
                      ((2 + (q >> 1)) ^ rm3) * 16 + (q & 1) * 8 };

  auto stage = [&](int bufb, const unsigned char* a_s,
                   const unsigned char* b_s, int kk) {
    #pragma unroll
    for (int i = 0; i < 2; ++i)
      gload_lds16(a_s + (long)i * 64 * H_DIM + kk,
                  smem + bufb + i * 4096 + tid * 16);
    #pragma unroll
    for (int i = 0; i < 2; ++i)
      gload_lds16(b_s + (long)i * 64 * H_DIM + kk,
                  smem + bufb + 8192 + i * 4096 + tid * 16);
  };

  // streaming-phase precompute
  const int srow  = tid >> 1;                  // 0..127
  const int shalf = tid & 1;
  const int cb0   = shalf * 64;
  const long grow   = (long)(brow * BM + srow);
  const long growVD = grow * V_DIM;
  const long tlim   = (long)N_ROWS * V_DIM - 4;
  const char* Lrow  = smem + LBASE + srow * 256;
  const int rsw     = (srow & 7) << 4;

  // prologue: stage first tile's k=0 into BUF0
  const unsigned char* bsrc = Wq + (long)(chunk * BN + srow4) * H_DIM + soff;
  stage(BUF0, asrc, bsrc, 0);

  #pragma unroll 1
  for (int vt = chunk; vt < VT_TOTAL; vt += NCHUNK) {
    const int vbase = vt * BN;
    const int v0 = vbase + wn * 64 + q * 4;
    const bool last = (vt + NCHUNK >= VT_TOTAL);
    const bool guard = (vt == VT_TOTAL - 1);
    const unsigned char* bsrc_next =
        Wq + (long)((vt + NCHUNK) * BN + srow4) * H_DIM + soff;

    f32x4 acc[4][4];
    #pragma unroll
    for (int a = 0; a < 4; ++a)
      #pragma unroll
      for (int b = 0; b < 4; ++b)
        acc[a][b] = (f32x4){0.f, 0.f, 0.f, 0.f};

    // ---- pipelined K-loop: counted vmcnt(4), raw barriers ----
    #pragma unroll
    for (int ks = 0; ks < NSTEP; ++ks) {
      const int cb = (ks & 1) ? BUF1 : BUF0;
      const int nb = cb ^ BUF1;
      if (ks < NSTEP - 1)
        stage(nb, asrc, bsrc, (ks + 1) * BK);
      else if (!last)
        stage(nb, asrc, bsrc_next, 0);   // next tile k0 -> BUF0; latency
                                         // hides under dump+stream
      if (ks == NSTEP - 1 && last) { VMC0(); } else { VMCNT4(); }
      BARRIER();

      #pragma unroll
      for (int s = 0; s < 2; ++s) {
        long xf[4], wf[4];
        #pragma unroll
        for (int a = 0; a < 4; ++a)
          xf[a] = *(const long*)(smem + cb + arow_b + a * 1024 + io[s]);
        #pragma unroll
        for (int b = 0; b < 4; ++b)
          wf[b] = *(const long*)(smem + cb + 8192 + brow_b + b * 1024 + io[s]);
        #pragma unroll
        for (int a = 0; a < 4; ++a)
          #pragma unroll
          for (int b = 0; b < 4; ++b)
            acc[a][b] = __builtin_amdgcn_mfma_f32_16x16x32_fp8_fp8(
                wf[b], xf[a], acc[a][b], 0, 0, 0);
      }
      LGKM0();
      BARRIER();
    }
    bsrc = bsrc_next;

    // ---- dump acc/32 + bias -> bf16 L tile (swizzled); acc dies ----
    f32x4 bp[4];
    #pragma unroll
    for (int b = 0; b < 4; ++b) {
      int bo = v0 + b * 16;
      bo = bo > (V_DIM - 4) ? (V_DIM - 4) : bo;
      bp[b] = *(const f32x4*)(bias + bo);
    }
    const int rmL = (c15 & 7) << 4;
    #pragma unroll
    for (int a = 0; a < 4; ++a) {
      const int row = wm * 64 + a * 16 + c15;      // row&7 == c15&7
      char* rb = smem + LBASE + row * 256;
      #pragma unroll
      for (int b = 0; b < 4; ++b) {
        uint2 w;
        w.x = (unsigned)f2bf(__builtin_fmaf(acc[a][b][0], WDESCALE, bp[b][0])) |
              ((unsigned)f2bf(__builtin_fmaf(acc[a][b][1], WDESCALE, bp[b][1])) << 16);
        w.y = (unsigned)f2bf(__builtin_fmaf(acc[a][b][2], WDESCALE, bp[b][2])) |
              ((unsigned)f2bf(__builtin_fmaf(acc[a][b][3], WDESCALE, bp[b][3])) << 16);
        const int o = wn * 128 + b * 32 + q * 8;
        *(uint2*)(rb + (o ^ rmL)) = w;
      }
    }
    LGKM0();
    BARRIER();

    // ---- streaming stats (next tile's k0 stage in flight under this) ----
    if (guard)
      stream_tile<true >(targets, Lrow, growVD, vbase, cb0, rsw, tlim,
                         mlr, slr, mtr, str, ddr);
    else
      stream_tile<false>(targets, Lrow, growVD, vbase, cb0, rsw, tlim,
                         mlr, slr, mtr, str, ddr);
    LGKM0();
    BARRIER();   // L fully read before next tile's dump overwrites
  }

  // merge the two halves of each row (lanes 2k / 2k+1)
  {
    float ml2 = __shfl_xor(mlr, 1);
    float sl2 = __shfl_xor(slr, 1);
    float mt2 = __shfl_xor(mtr, 1);
    float st2 = __shfl_xor(str, 1);
    float dd2 = __shfl_xor(ddr, 1);
    float nm = fmaxf(mlr, ml2);
    float slo = slr * exp2f((mlr - nm) * LOG2E) + sl2 * exp2f((ml2 - nm) * LOG2E);
    float nmt = fmaxf(mtr, mt2);
    float e1 = exp2f((mtr - nmt) * LOG2E);
    float e2 = exp2f((mt2 - nmt) * LOG2E);
    float sto = str * e1 + st2 * e2;
    float ddo = ddr * e1 + dd2 * e2;
    if (shalf == 0) {
      float* o = partials + (grow * NCHUNK + chunk) * 5;
      o[0] = nm; o[1] = slo; o[2] = nmt; o[3] = sto; o[4] = ddo;
    }
  }
}

// ---------------- kernel C: merge partials -> per-row loss ----------------
__global__ void rowloss_kernel(const float* __restrict__ partials,
                               float* __restrict__ rowloss) {
  int r = blockIdx.x * blockDim.x + threadIdx.x;
  if (r >= N_ROWS) return;
  const float* p = partials + (long)r * NCHUNK * 5;
  float ml = -1e30f, sl = 0.f, mt = -1e30f, st = 0.f, dd = 0.f;
  for (int c = 0; c < NCHUNK; ++c) {
    float ml2 = p[0], sl2 = p[1], mt2 = p[2], st2 = p[3], dd2 = p[4];
    p += 5;
    float nm = fmaxf(ml, ml2);
    sl = sl * exp2f((ml - nm) * LOG2E) + sl2 * exp2f((ml2 - nm) * LOG2E);
    ml = nm;
    float nmt = fmaxf(mt, mt2);
    float e1 = exp2f((mt - nmt) * LOG2E);
    float e2 = exp2f((mt2 - nmt) * LOG2E);
    st = st * e1 + st2 * e2;
    dd = dd * e1 + dd2 * e2;
    mt = nmt;
  }
  float lse = ml + logf(sl);
  rowloss[r] = lse - dd / st;
}

// ---------------- kernel D: final scalar reduce ---------------------------
__global__ void final_kernel(const float* __restrict__ rowloss,
                             float* __restrict__ out) {
  __shared__ float sm[4];
  float s = 0.f;
  for (int i = threadIdx.x; i < N_ROWS; i += 256) s += rowloss[i];
  #pragma unroll
  for (int off = 32; off > 0; off >>= 1) s += __shfl_down(s, off);
  if ((threadIdx.x & 63) == 0) sm[threadIdx.x >> 6] = s;
  __syncthreads();
  if (threadIdx.x == 0) out[0] = (sm[0] + sm[1] + sm[2] + sm[3]) * (1.0f / (float)N_ROWS);
}

extern "C" void kernel_launch(void* const* d_in, const int* in_sizes, int n_in,
                              void* d_out, int out_size, void* d_ws, size_t ws_size,
                              hipStream_t stream) {
  const float* x       = (const float*)d_in[0];   // [4096, 512]
  const float* targets = (const float*)d_in[1];   // [4096, 50257]
  const float* weight  = (const float*)d_in[2];   // [50257, 512]
  const float* bias    = (const float*)d_in[3];   // [50257]
  float* out = (float*)d_out;

  char* ws = (char*)d_ws;
  unsigned char* Wq = (unsigned char*)ws;                       // 25,755,648 B
  size_t off = (size_t)V_PAD * H_DIM;
  unsigned char* Xq = (unsigned char*)(ws + off);               //  2,097,152 B
  off += (size_t)N_ROWS * H_DIM;
  off = (off + 255) & ~(size_t)255;
  float* partials = (float*)(ws + off);                         // 10,731,520 B
  off += (size_t)N_ROWS * NCHUNK * 5 * sizeof(float);
  float* rowloss = (float*)(ws + off);                          //     16,384 B

  convert_kernel<<<13600, 256, 0, stream>>>(x, weight, Xq, Wq);
  dim3 grid(N_ROWS / BM, NCHUNK);
  fused_kernel<<<grid, 256, 0, stream>>>(Xq, Wq, bias, targets, partials);
  rowloss_kernel<<<N_ROWS / 256, 256, 0, stream>>>(partials, rowloss);
  final_kernel<<<1, 256, 0, stream>>>(rowloss, out);
}